// Round 14
// baseline (231.489 us; speedup 1.0000x reference)
//
#include <hip/hip_runtime.h>
#include <hip/hip_bf16.h>
#include <hip/hip_fp16.h>

#define N_NODES 100000
#define N_EDGES 1600000
#define DIM_IN 128
#define DIM_OUT 64

#define NB 391      // coarse buckets: row >> 8 (256 rows each; last has 160)
#define NCHUNK 391  // edge chunks
#define CHUNK 4096  // edges per chunk (NCHUNK*CHUNK >= N_EDGES)
#define BCAP 5120   // max edges per bucket (mean 4092, sd ~64)
#define EPCAP 6144  // fixed ep region per bucket (padded total mean ~4990)

typedef unsigned int uint;
typedef unsigned short ushort;
typedef _Float16 half8 __attribute__((ext_vector_type(8)));
typedef float f32x4 __attribute__((ext_vector_type(4)));

__device__ inline ushort f2h(float f) {
    __half h = __float2half(f);  // round-to-nearest-even
    return *reinterpret_cast<ushort*>(&h);
}

// ---------------- CSR build: two-level counting sort, 8-padded rows ----------------

__global__ __launch_bounds__(256) void chunk_hist_kernel(const int* __restrict__ erow,
                                                         int* __restrict__ counts, int E) {
    __shared__ int hist[NB];
    const int t = threadIdx.x, c = blockIdx.x;
    for (int b = t; b < NB; b += 256) hist[b] = 0;
    __syncthreads();
    const int eb = c * CHUNK;
#pragma unroll
    for (int i = 0; i < CHUNK / 256; ++i) {
        int e = eb + i * 256 + t;
        if (e < E) atomicAdd(&hist[erow[e] >> 8], 1);
    }
    __syncthreads();
    for (int b = t; b < NB; b += 256) counts[b * NCHUNK + c] = hist[b];
}

__global__ __launch_bounds__(512) void bucket_scan_kernel(const int* __restrict__ counts,
                                                          int* __restrict__ offnb,
                                                          int* __restrict__ tot) {
    __shared__ int s[512];
    const int b = blockIdx.x, t = threadIdx.x;
    int v = (t < NCHUNK) ? counts[b * NCHUNK + t] : 0;
    s[t] = v;
    __syncthreads();
#pragma unroll
    for (int o = 1; o < 512; o <<= 1) {
        int x = s[t];
        int y = (t >= o) ? s[t - o] : 0;
        __syncthreads();
        s[t] = x + y;
        __syncthreads();
    }
    if (t < NCHUNK) offnb[b * NCHUNK + t] = s[t] - v;
    if (t == 511) tot[b] = s[511];
}

__global__ __launch_bounds__(512) void base_scan_kernel(const int* __restrict__ tot,
                                                        int* __restrict__ bbase) {
    __shared__ int s[512];
    const int t = threadIdx.x;
    int v = (t < NB) ? tot[t] : 0;
    s[t] = v;
    __syncthreads();
#pragma unroll
    for (int o = 1; o < 512; o <<= 1) {
        int x = s[t];
        int y = (t >= o) ? s[t - o] : 0;
        __syncthreads();
        s[t] = x + y;
        __syncthreads();
    }
    if (t < NB) bbase[t] = s[t] - v;
    if (t == 511) bbase[NB] = s[511];
}

__global__ __launch_bounds__(512) void coarse_scatter_kernel(const int* __restrict__ erow,
                                                             const int* __restrict__ ecol,
                                                             const float* __restrict__ eval,
                                                             const int* __restrict__ offnb,
                                                             const int* __restrict__ bbase,
                                                             uint* __restrict__ keyOut,
                                                             float* __restrict__ valOut, int E) {
    __shared__ int hist[NB];
    __shared__ int segOff[NB];
    __shared__ int localOff[NB];
    __shared__ int sc[512];
    __shared__ int idxL[CHUNK];
    __shared__ int gaddrL[CHUNK];

    const int t = threadIdx.x, c = blockIdx.x;
    for (int b = t; b < NB; b += 512) {
        hist[b] = 0;
        segOff[b] = bbase[b] + offnb[b * NCHUNK + c];
    }
    __syncthreads();
    const int eb = c * CHUNK;
    uint bq[CHUNK / 512];
#pragma unroll
    for (int i = 0; i < CHUNK / 512; ++i) {
        int e = eb + i * 512 + t;
        if (e < E) {
            int b = erow[e] >> 8;
            int q = atomicAdd(&hist[b], 1);
            bq[i] = ((uint)b << 16) | (uint)q;
        } else {
            bq[i] = 0xFFFFFFFFu;
        }
    }
    __syncthreads();
    int v = (t < NB) ? hist[t] : 0;
    sc[t] = v;
    __syncthreads();
#pragma unroll
    for (int o = 1; o < 512; o <<= 1) {
        int x = sc[t];
        int y = (t >= o) ? sc[t - o] : 0;
        __syncthreads();
        sc[t] = x + y;
        __syncthreads();
    }
    if (t < NB) localOff[t] = sc[t] - v;
    __syncthreads();
#pragma unroll
    for (int i = 0; i < CHUNK / 512; ++i) {
        if (bq[i] != 0xFFFFFFFFu) {
            int b = bq[i] >> 16;
            int q = bq[i] & 0xFFFF;
            int s = localOff[b] + q;
            idxL[s] = eb + i * 512 + t;
            gaddrL[s] = segOff[b] + q;
        }
    }
    __syncthreads();
    const int m = min(CHUNK, E - eb);
    for (int s = t; s < m; s += 512) {
        int e = idxL[s];
        int g = gaddrL[s];
        keyOut[g] = ((uint)(erow[e] & 255) << 17) | (uint)ecol[e];
        valOut[g] = eval[e];
    }
}

// Fine sort: per-bucket 256-bin counting sort by row; rows padded to multiples of 8.
// ep.x = ((row & 15) << 17) | col.
__global__ __launch_bounds__(256) void fine_sort_kernel(const uint* __restrict__ keyOut,
                                                        const float* __restrict__ valOut,
                                                        const int* __restrict__ bbase,
                                                        int* __restrict__ row_ptr,
                                                        int* __restrict__ row_len,
                                                        int2* __restrict__ ep) {
    __shared__ uint keyL[BCAP];
    __shared__ int hist[256];
    __shared__ int offs[256];
    const int b = blockIdx.x, t = threadIdx.x;
    const int s0 = bbase[b], s1 = bbase[b + 1];
    const int m = min(s1 - s0, BCAP);
    hist[t] = 0;
    __syncthreads();
    for (int j = t; j < m; j += 256) {
        uint k = keyOut[s0 + j];
        keyL[j] = k;
        atomicAdd(&hist[k >> 17], 1);
    }
    __syncthreads();
    const int deg = hist[t];
    const int pdeg = (deg + 7) & ~7;
    offs[t] = pdeg;
    __syncthreads();
#pragma unroll
    for (int o = 1; o < 256; o <<= 1) {
        int x = offs[t];
        int y = (t >= o) ? offs[t - o] : 0;
        __syncthreads();
        offs[t] = x + y;
        __syncthreads();
    }
    const int pexcl = offs[t] - pdeg;
    const int base = b * EPCAP;
    const int row = b * 256 + t;
    if (row < N_NODES) {
        row_ptr[row] = base + pexcl;
        row_len[row] = pdeg;
    }
    hist[t] = pexcl;
    __syncthreads();
    for (int j = t; j < m; j += 256) {
        uint k = keyL[j];
        int r8 = (int)(k >> 17);
        int pos = atomicAdd(&hist[r8], 1);
        ep[base + pos] = make_int2((int)(((uint)(r8 & 15) << 17) | (k & 0x1FFFFu)),
                                   __float_as_int(valOut[s0 + j]));
    }
    __syncthreads();
    for (int j = pexcl + deg; j < pexcl + pdeg; ++j)
        ep[base + j] = make_int2((int)((uint)(t & 15) << 17), 0);
}

// ---------------- f32 -> f16 conversion of both weights in one launch ----------------

__global__ __launch_bounds__(256) void cvt_weights_kernel(const float* __restrict__ W1,
                                                          const float* __restrict__ W2,
                                                          uint* __restrict__ W1h,
                                                          uint* __restrict__ W2h) {
    int i = blockIdx.x * 256 + threadIdx.x;  // 2048 for W1, 1024 for W2
    const float* in;
    uint* outp;
    int j;
    if (i < 2048) { in = W1; outp = W1h; j = i; }
    else if (i < 3072) { in = W2; outp = W2h; j = i - 2048; }
    else return;
    const float4* in4 = reinterpret_cast<const float4*>(in) + (size_t)j * 2;
    float4 a = in4[0];
    float4 b = in4[1];
    uint4 o;
    o.x = (uint)f2h(a.x) | ((uint)f2h(a.y) << 16);
    o.y = (uint)f2h(a.z) | ((uint)f2h(a.w) << 16);
    o.z = (uint)f2h(b.x) | ((uint)f2h(b.y) << 16);
    o.w = (uint)f2h(b.z) | ((uint)f2h(b.w) << 16);
    reinterpret_cast<uint4*>(outp)[j] = o;
}

// ---------------- MFMA GEMM: XW1 = f16(X @ W1^T), K=128, f32 in / f16 out ----------------

__global__ __launch_bounds__(256) void mfma_gemm128_kernel(const float* __restrict__ Af,
                                                           const uint* __restrict__ Wh,
                                                           uint* __restrict__ Out, int M) {
    __shared__ __align__(16) ushort sA[128 * 128];
    __shared__ __align__(16) ushort sB[128 * 128];

    const int t = threadIdx.x;
    const int l = t & 63;
    const int w = t >> 6;
    const int row0 = blockIdx.x * 128;
    const int lr = l & 15;
    const int lk = l >> 4;

#pragma unroll
    for (int i = 0; i < 16; ++i) {
        int fid = i * 256 + t;
        int row = fid >> 5, q4 = fid & 31;
        int gr = row0 + row;
        float4 v = make_float4(0.f, 0.f, 0.f, 0.f);
        if (gr < M) v = *reinterpret_cast<const float4*>(Af + (size_t)gr * 128 + q4 * 4);
        uint2 p;
        p.x = (uint)f2h(v.x) | ((uint)f2h(v.y) << 16);
        p.y = (uint)f2h(v.z) | ((uint)f2h(v.w) << 16);
        int slot = q4 >> 1;
        *reinterpret_cast<uint2*>(&sA[row * 128 + ((slot ^ (row & 7)) << 3) + (q4 & 1) * 4]) = p;
    }
#pragma unroll
    for (int i = 0; i < 8; ++i) {
        int fid = i * 256 + t;
        int row = fid >> 4, slot = fid & 15;
        uint4 v = reinterpret_cast<const uint4*>(Wh)[row * 16 + slot];
        *reinterpret_cast<uint4*>(&sB[row * 128 + ((slot ^ (row & 7)) << 3)]) = v;
    }
    __syncthreads();

    f32x4 acc[2][8];
#pragma unroll
    for (int rf = 0; rf < 2; ++rf)
#pragma unroll
        for (int cf = 0; cf < 8; ++cf) acc[rf][cf] = (f32x4){0.f, 0.f, 0.f, 0.f};

    half8 aF[2][4];
#pragma unroll
    for (int rf = 0; rf < 2; ++rf) {
        int row = w * 32 + rf * 16 + lr;
#pragma unroll
        for (int kc = 0; kc < 4; ++kc) {
            int slot = kc * 4 + lk;
            aF[rf][kc] = *reinterpret_cast<const half8*>(&sA[row * 128 + ((slot ^ (row & 7)) << 3)]);
        }
    }
#pragma unroll
    for (int cf = 0; cf < 8; ++cf) {
        int col = cf * 16 + lr;
#pragma unroll
        for (int kc = 0; kc < 4; ++kc) {
            int slot = kc * 4 + lk;
            half8 bF = *reinterpret_cast<const half8*>(&sB[col * 128 + ((slot ^ (col & 7)) << 3)]);
            acc[0][cf] = __builtin_amdgcn_mfma_f32_16x16x32_f16(aF[0][kc], bF, acc[0][cf], 0, 0, 0);
            acc[1][cf] = __builtin_amdgcn_mfma_f32_16x16x32_f16(aF[1][kc], bF, acc[1][cf], 0, 0, 0);
        }
    }
    __syncthreads();

    ushort* sOut = sA;
#pragma unroll
    for (int rf = 0; rf < 2; ++rf)
#pragma unroll
        for (int cf = 0; cf < 8; ++cf)
#pragma unroll
            for (int reg = 0; reg < 4; ++reg) {
                int row = w * 32 + rf * 16 + lk * 4 + reg;
                int col = cf * 16 + lr;
                sOut[row * 128 + col] = f2h(acc[rf][cf][reg]);
            }
    __syncthreads();
#pragma unroll
    for (int i = 0; i < 8; ++i) {
        int fid = i * 256 + t;
        int row = fid >> 4, q = fid & 15;
        int gr = row0 + row;
        if (gr < M)
            reinterpret_cast<uint4*>(Out)[(size_t)gr * 16 + q] =
                *reinterpret_cast<const uint4*>(&sOut[row * 128 + q * 8]);
    }
}

// ---------------- Fused SpMM1 + MLP2: P = tanh(SpMM(A,XW1)) @ W2^T ----------------
// 64 rows/block, wave w owns rows w*16..w*16+15 == exactly its MFMA tile's rows.
// All LDS traffic is wave-local (own sH/sP quadrants) -> ZERO __syncthreads; waves
// are fully independent so degree imbalance is absorbed by 6250 wave-tasks.
// W2 read directly from global in the MFMA phase (16KB, L1/L2-resident).

__global__ __launch_bounds__(256) void spmm1_fused_kernel(const int2* __restrict__ ep,
                                                          const int* __restrict__ row_ptr,
                                                          const int* __restrict__ row_len,
                                                          const uint* __restrict__ T,
                                                          const uint* __restrict__ W2h,
                                                          uint* __restrict__ Ph, int M) {
    __shared__ __align__(16) ushort sH[64 * 128];  // 16 KB, swizzled, wave-local quadrants
    __shared__ __align__(16) ushort sP[64 * 64];   // 8 KB, row-major, wave-local quadrants

    const int t = threadIdx.x;
    const int l = t & 63;
    const int w = t >> 6;
    const int lr = l & 15;
    const int lk = l >> 4;
    const int row0 = blockIdx.x * 64;
    const int wrow0 = w * 16;  // this wave's local row base (multiple of 16 -> &7 unaffected)

    uint* sHu = reinterpret_cast<uint*>(sH);
    // ---- gather phase: 16 rows, register accumulation, tail-free ----
    for (int rr = 0; rr < 16; ++rr) {
        const int lrow = wrow0 + rr;
        const int r = row0 + lrow;
        float a0x = 0.f, a0y = 0.f, a1x = 0.f, a1y = 0.f;
        if (r < M) {
            const int beg = row_ptr[r];
            const int end = beg + row_len[r];
            for (int e = beg; e < end; e += 8) {
                int2 cv[8];
                uint xu[8];
#pragma unroll
                for (int i = 0; i < 8; ++i) cv[i] = ep[e + i];
#pragma unroll
                for (int i = 0; i < 8; ++i) xu[i] = T[(size_t)(cv[i].x & 0x1FFFF) * 64 + l];
#pragma unroll
                for (int i = 0; i < 8; ++i) {
                    float v = __int_as_float(cv[i].y);
                    __half2 h2 = *reinterpret_cast<__half2*>(&xu[i]);
                    float2 f = __half22float2(h2);
                    if (i & 1) { a1x += v * f.x; a1y += v * f.y; }
                    else       { a0x += v * f.x; a0y += v * f.y; }
                }
            }
        }
        // lane l holds dims 2l, 2l+1 of H row lrow -> 16B slot l>>2, uint word l&3
        const uint hv = (uint)f2h(tanhf(a0x + a1x)) | ((uint)f2h(tanhf(a0y + a1y)) << 16);
        const int slot = l >> 2;
        sHu[lrow * 64 + ((slot ^ (lrow & 7)) << 2) + (l & 3)] = hv;
    }
    __threadfence_block();  // wave-local LDS write->read ordering (no cross-wave deps)

    // ---- MFMA phase: A fragments once, 4 col-tiles vs W2 direct from global ----
    half8 aF[4];
    {
        const int arow = wrow0 + lr;
#pragma unroll
        for (int kc = 0; kc < 4; ++kc) {
            const int slot = kc * 4 + lk;
            aF[kc] = *reinterpret_cast<const half8*>(&sH[arow * 128 + ((slot ^ (arow & 7)) << 3)]);
        }
    }
    f32x4 acc[4];
#pragma unroll
    for (int ct = 0; ct < 4; ++ct) acc[ct] = (f32x4){0.f, 0.f, 0.f, 0.f};
#pragma unroll
    for (int ct = 0; ct < 4; ++ct) {
        const int col = ct * 16 + lr;
#pragma unroll
        for (int kc = 0; kc < 4; ++kc) {
            const uint4 wv = reinterpret_cast<const uint4*>(W2h)[col * 16 + kc * 4 + lk];
            half8 bF = *reinterpret_cast<const half8*>(&wv);
            acc[ct] = __builtin_amdgcn_mfma_f32_16x16x32_f16(aF[kc], bF, acc[ct], 0, 0, 0);
        }
    }
    // C layout: col = l&15, row = (l>>4)*4 + reg
#pragma unroll
    for (int ct = 0; ct < 4; ++ct)
#pragma unroll
        for (int reg = 0; reg < 4; ++reg)
            sP[(wrow0 + lk * 4 + reg) * 64 + ct * 16 + lr] = f2h(acc[ct][reg]);
    __threadfence_block();

    // ---- copy-out: wave-local 16 rows x 8 uint4 ----
#pragma unroll
    for (int i = 0; i < 2; ++i) {
        const int fid = i * 64 + l;
        const int prow = fid >> 3, q = fid & 7;
        const int gr = row0 + wrow0 + prow;
        if (gr < M)
            reinterpret_cast<uint4*>(Ph)[(size_t)gr * 8 + q] =
                *reinterpret_cast<const uint4*>(&sP[(wrow0 + prow) * 64 + q * 8]);
    }
}

// ---------------- SpMM 64-dim f16 gather + tanh -> f32 out (tail-free) ----------------

__global__ __launch_bounds__(256) void spmm2_kernel(const int2* __restrict__ ep,
                                                    const int* __restrict__ row_ptr,
                                                    const int* __restrict__ row_len,
                                                    const ushort* __restrict__ Ph,
                                                    float* __restrict__ out) {
    int wave = threadIdx.x >> 6;
    int lane = threadIdx.x & 63;
    int r = blockIdx.x * 4 + wave;
    if (r >= N_NODES) return;
    int beg = row_ptr[r];
    int end = beg + row_len[r];
    float acc0 = 0.f, acc1 = 0.f;
    for (int e = beg; e < end; e += 8) {
        int2 cv[8];
        ushort xu[8];
#pragma unroll
        for (int i = 0; i < 8; ++i) cv[i] = ep[e + i];
#pragma unroll
        for (int i = 0; i < 8; ++i) xu[i] = Ph[(size_t)(cv[i].x & 0x1FFFF) * 64 + lane];
#pragma unroll
        for (int i = 0; i < 8; ++i) {
            float v = __int_as_float(cv[i].y);
            __half h = *reinterpret_cast<__half*>(&xu[i]);
            float x = __half2float(h);
            if (i & 1) acc1 += v * x;
            else       acc0 += v * x;
        }
    }
    out[(size_t)r * DIM_OUT + lane] = tanhf(acc0 + acc1);
}

// ---------------- launch ----------------

extern "C" void kernel_launch(void* const* d_in, const int* in_sizes, int n_in,
                              void* d_out, int out_size, void* d_ws, size_t ws_size,
                              hipStream_t stream) {
    const float* X = (const float*)d_in[0];
    const float* W1 = (const float*)d_in[1];
    const float* W2 = (const float*)d_in[2];
    const float* evals = (const float*)d_in[3];
    const int* erow = (const int*)d_in[4];
    const int* ecol = (const int*)d_in[5];
    float* out = (float*)d_out;

    const int N = N_NODES;
    const int E = N_EDGES;

    char* ws = (char*)d_ws;
    size_t off = 0;
    auto alloc = [&](size_t bytes) {
        size_t o = off;
        off = (off + bytes + 255) & ~(size_t)255;
        return o;
    };
    size_t o_counts = alloc((size_t)NB * NCHUNK * 4);
    size_t o_offnb = alloc((size_t)NB * NCHUNK * 4);
    size_t o_tot = alloc((size_t)NB * 4);
    size_t o_bbase = alloc((size_t)(NB + 1) * 4);
    size_t o_rowptr = alloc((size_t)N * 4);
    size_t o_rowlen = alloc((size_t)N * 4);
    size_t o_ep = alloc((size_t)NB * EPCAP * 8);  // 19.2MB padded CSR
    size_t o_key = alloc((size_t)E * 4);
    size_t o_val = alloc((size_t)E * 4);
    size_t o_xw1 = alloc((size_t)N * 64 * 4);  // XW1h [N,128] f16
    size_t o_ph = alloc((size_t)N * 32 * 4);   // Ph   [N,64]  f16
    size_t o_w1h = alloc((size_t)128 * 64 * 4);
    size_t o_w2h = alloc((size_t)64 * 64 * 4);
    (void)ws_size;

    int* counts = (int*)(ws + o_counts);
    int* offnb = (int*)(ws + o_offnb);
    int* tot = (int*)(ws + o_tot);
    int* bbase = (int*)(ws + o_bbase);
    int* row_ptr = (int*)(ws + o_rowptr);
    int* row_len = (int*)(ws + o_rowlen);
    int2* ep = (int2*)(ws + o_ep);
    uint* keyOut = (uint*)(ws + o_key);
    float* valOut = (float*)(ws + o_val);
    uint* XW1h = (uint*)(ws + o_xw1);
    uint* Ph = (uint*)(ws + o_ph);
    uint* W1h = (uint*)(ws + o_w1h);
    uint* W2h = (uint*)(ws + o_w2h);

    const int gemm_grid = (N + 127) / 128;  // 782
    const int spmm2_grid = (N + 3) / 4;     // 25000
    const int fused_grid = (N + 63) / 64;   // 1563

    // weight conversions (one launch) + XW1 = f16(X @ W1^T)
    cvt_weights_kernel<<<12, 256, 0, stream>>>(W1, W2, W1h, W2h);
    mfma_gemm128_kernel<<<gemm_grid, 256, 0, stream>>>(X, W1h, XW1h, N);

    // CSR build (deterministic counting sort; rows padded to multiples of 8)
    chunk_hist_kernel<<<NCHUNK, 256, 0, stream>>>(erow, counts, E);
    bucket_scan_kernel<<<NB, 512, 0, stream>>>(counts, offnb, tot);
    base_scan_kernel<<<1, 512, 0, stream>>>(tot, bbase);
    coarse_scatter_kernel<<<NCHUNK, 512, 0, stream>>>(erow, ecol, evals, offnb, bbase,
                                                      keyOut, valOut, E);
    fine_sort_kernel<<<NB, 256, 0, stream>>>(keyOut, valOut, bbase, row_ptr, row_len, ep);

    // P = tanh(SpMM(A, XW1)) @ W2^T   [fused, barrier-free, wave-independent]
    spmm1_fused_kernel<<<fused_grid, 256, 0, stream>>>(ep, row_ptr, row_len, XW1h, W2h, Ph, N);
    // out = tanh(SpMM(A, P))
    spmm2_kernel<<<spmm2_grid, 256, 0, stream>>>(ep, row_ptr, row_len, (const ushort*)Ph, out);
}

// Round 15
// 196.331 us; speedup vs baseline: 1.1791x; 1.1791x over previous
//
#include <hip/hip_runtime.h>
#include <hip/hip_bf16.h>
#include <hip/hip_fp16.h>

#define N_NODES 100000
#define N_EDGES 1600000
#define DIM_IN 128
#define DIM_OUT 64

#define NB 391      // coarse buckets: row >> 8 (256 rows each; last has 160)
#define NCHUNK 391  // edge chunks
#define CHUNK 4096  // edges per chunk (NCHUNK*CHUNK >= N_EDGES)
#define BCAP 5120   // max edges per bucket (mean 4092, sd ~64)
#define EPCAP 6144  // fixed ep region per bucket (padded total mean ~4990)

typedef unsigned int uint;
typedef unsigned short ushort;
typedef _Float16 half8 __attribute__((ext_vector_type(8)));
typedef float f32x4 __attribute__((ext_vector_type(4)));

__device__ inline ushort f2h(float f) {
    __half h = __float2half(f);  // round-to-nearest-even
    return *reinterpret_cast<ushort*>(&h);
}

// ---------------- CSR build: two-level counting sort, 8-padded rows ----------------
// chunk_hist also converts W2 -> f16 in block 0 (tiny; needed much later by fused).

__global__ __launch_bounds__(256) void chunk_hist_kernel(const int* __restrict__ erow,
                                                         int* __restrict__ counts,
                                                         const float* __restrict__ W2,
                                                         uint* __restrict__ W2h, int E) {
    __shared__ int hist[NB];
    const int t = threadIdx.x, c = blockIdx.x;
    for (int b = t; b < NB; b += 256) hist[b] = 0;
    __syncthreads();
    const int eb = c * CHUNK;
#pragma unroll
    for (int i = 0; i < CHUNK / 256; ++i) {
        int e = eb + i * 256 + t;
        if (e < E) atomicAdd(&hist[erow[e] >> 8], 1);
    }
    __syncthreads();
    for (int b = t; b < NB; b += 256) counts[b * NCHUNK + c] = hist[b];
    if (c == 0) {
        // W2: 64x128 f32 -> packed f16 (1024 uint4 outputs, 8 floats each)
        for (int j = t; j < 1024; j += 256) {
            const float4* in4 = reinterpret_cast<const float4*>(W2) + (size_t)j * 2;
            float4 a = in4[0];
            float4 b = in4[1];
            uint4 o;
            o.x = (uint)f2h(a.x) | ((uint)f2h(a.y) << 16);
            o.y = (uint)f2h(a.z) | ((uint)f2h(a.w) << 16);
            o.z = (uint)f2h(b.x) | ((uint)f2h(b.y) << 16);
            o.w = (uint)f2h(b.z) | ((uint)f2h(b.w) << 16);
            reinterpret_cast<uint4*>(W2h)[j] = o;
        }
    }
}

__global__ __launch_bounds__(512) void bucket_scan_kernel(const int* __restrict__ counts,
                                                          int* __restrict__ offnb,
                                                          int* __restrict__ tot) {
    __shared__ int s[512];
    const int b = blockIdx.x, t = threadIdx.x;
    int v = (t < NCHUNK) ? counts[b * NCHUNK + t] : 0;
    s[t] = v;
    __syncthreads();
#pragma unroll
    for (int o = 1; o < 512; o <<= 1) {
        int x = s[t];
        int y = (t >= o) ? s[t - o] : 0;
        __syncthreads();
        s[t] = x + y;
        __syncthreads();
    }
    if (t < NCHUNK) offnb[b * NCHUNK + t] = s[t] - v;
    if (t == 511) tot[b] = s[511];
}

__global__ __launch_bounds__(512) void base_scan_kernel(const int* __restrict__ tot,
                                                        int* __restrict__ bbase) {
    __shared__ int s[512];
    const int t = threadIdx.x;
    int v = (t < NB) ? tot[t] : 0;
    s[t] = v;
    __syncthreads();
#pragma unroll
    for (int o = 1; o < 512; o <<= 1) {
        int x = s[t];
        int y = (t >= o) ? s[t - o] : 0;
        __syncthreads();
        s[t] = x + y;
        __syncthreads();
    }
    if (t < NB) bbase[t] = s[t] - v;
    if (t == 511) bbase[NB] = s[511];
}

__global__ __launch_bounds__(512) void coarse_scatter_kernel(const int* __restrict__ erow,
                                                             const int* __restrict__ ecol,
                                                             const float* __restrict__ eval,
                                                             const int* __restrict__ offnb,
                                                             const int* __restrict__ bbase,
                                                             uint* __restrict__ keyOut,
                                                             float* __restrict__ valOut, int E) {
    __shared__ int hist[NB];
    __shared__ int segOff[NB];
    __shared__ int localOff[NB];
    __shared__ int sc[512];
    __shared__ int idxL[CHUNK];
    __shared__ int gaddrL[CHUNK];

    const int t = threadIdx.x, c = blockIdx.x;
    for (int b = t; b < NB; b += 512) {
        hist[b] = 0;
        segOff[b] = bbase[b] + offnb[b * NCHUNK + c];
    }
    __syncthreads();
    const int eb = c * CHUNK;
    uint bq[CHUNK / 512];
#pragma unroll
    for (int i = 0; i < CHUNK / 512; ++i) {
        int e = eb + i * 512 + t;
        if (e < E) {
            int b = erow[e] >> 8;
            int q = atomicAdd(&hist[b], 1);
            bq[i] = ((uint)b << 16) | (uint)q;
        } else {
            bq[i] = 0xFFFFFFFFu;
        }
    }
    __syncthreads();
    int v = (t < NB) ? hist[t] : 0;
    sc[t] = v;
    __syncthreads();
#pragma unroll
    for (int o = 1; o < 512; o <<= 1) {
        int x = sc[t];
        int y = (t >= o) ? sc[t - o] : 0;
        __syncthreads();
        sc[t] = x + y;
        __syncthreads();
    }
    if (t < NB) localOff[t] = sc[t] - v;
    __syncthreads();
#pragma unroll
    for (int i = 0; i < CHUNK / 512; ++i) {
        if (bq[i] != 0xFFFFFFFFu) {
            int b = bq[i] >> 16;
            int q = bq[i] & 0xFFFF;
            int s = localOff[b] + q;
            idxL[s] = eb + i * 512 + t;
            gaddrL[s] = segOff[b] + q;
        }
    }
    __syncthreads();
    const int m = min(CHUNK, E - eb);
    for (int s = t; s < m; s += 512) {
        int e = idxL[s];
        int g = gaddrL[s];
        keyOut[g] = ((uint)(erow[e] & 255) << 17) | (uint)ecol[e];
        valOut[g] = eval[e];
    }
}

// Fine sort: per-bucket 256-bin counting sort by row; rows padded to multiples of 8.
// ep.x = ((row & 15) << 17) | col.
__global__ __launch_bounds__(256) void fine_sort_kernel(const uint* __restrict__ keyOut,
                                                        const float* __restrict__ valOut,
                                                        const int* __restrict__ bbase,
                                                        int* __restrict__ row_ptr,
                                                        int* __restrict__ row_len,
                                                        int2* __restrict__ ep) {
    __shared__ uint keyL[BCAP];
    __shared__ int hist[256];
    __shared__ int offs[256];
    const int b = blockIdx.x, t = threadIdx.x;
    const int s0 = bbase[b], s1 = bbase[b + 1];
    const int m = min(s1 - s0, BCAP);
    hist[t] = 0;
    __syncthreads();
    for (int j = t; j < m; j += 256) {
        uint k = keyOut[s0 + j];
        keyL[j] = k;
        atomicAdd(&hist[k >> 17], 1);
    }
    __syncthreads();
    const int deg = hist[t];
    const int pdeg = (deg + 7) & ~7;
    offs[t] = pdeg;
    __syncthreads();
#pragma unroll
    for (int o = 1; o < 256; o <<= 1) {
        int x = offs[t];
        int y = (t >= o) ? offs[t - o] : 0;
        __syncthreads();
        offs[t] = x + y;
        __syncthreads();
    }
    const int pexcl = offs[t] - pdeg;
    const int base = b * EPCAP;
    const int row = b * 256 + t;
    if (row < N_NODES) {
        row_ptr[row] = base + pexcl;
        row_len[row] = pdeg;
    }
    hist[t] = pexcl;
    __syncthreads();
    for (int j = t; j < m; j += 256) {
        uint k = keyL[j];
        int r8 = (int)(k >> 17);
        int pos = atomicAdd(&hist[r8], 1);
        ep[base + pos] = make_int2((int)(((uint)(r8 & 15) << 17) | (k & 0x1FFFFu)),
                                   __float_as_int(valOut[s0 + j]));
    }
    __syncthreads();
    for (int j = pexcl + deg; j < pexcl + pdeg; ++j)
        ep[base + j] = make_int2((int)((uint)(t & 15) << 17), 0);
}

// ---------------- MFMA GEMM: XW1 = f16(X @ W1^T), K=128, f32 in (both), f16 out ------

__global__ __launch_bounds__(256) void mfma_gemm128_kernel(const float* __restrict__ Af,
                                                           const float* __restrict__ W1f,
                                                           uint* __restrict__ Out, int M) {
    __shared__ __align__(16) ushort sA[128 * 128];
    __shared__ __align__(16) ushort sB[128 * 128];

    const int t = threadIdx.x;
    const int l = t & 63;
    const int w = t >> 6;
    const int row0 = blockIdx.x * 128;
    const int lr = l & 15;
    const int lk = l >> 4;

#pragma unroll
    for (int i = 0; i < 16; ++i) {
        int fid = i * 256 + t;
        int row = fid >> 5, q4 = fid & 31;
        int gr = row0 + row;
        float4 v = make_float4(0.f, 0.f, 0.f, 0.f);
        if (gr < M) v = *reinterpret_cast<const float4*>(Af + (size_t)gr * 128 + q4 * 4);
        uint2 p;
        p.x = (uint)f2h(v.x) | ((uint)f2h(v.y) << 16);
        p.y = (uint)f2h(v.z) | ((uint)f2h(v.w) << 16);
        int slot = q4 >> 1;
        *reinterpret_cast<uint2*>(&sA[row * 128 + ((slot ^ (row & 7)) << 3) + (q4 & 1) * 4]) = p;
    }
    // W1 staged from f32 with inline conversion (same pattern as sA)
#pragma unroll
    for (int i = 0; i < 16; ++i) {
        int fid = i * 256 + t;
        int row = fid >> 5, q4 = fid & 31;
        float4 v = *reinterpret_cast<const float4*>(W1f + (size_t)row * 128 + q4 * 4);
        uint2 p;
        p.x = (uint)f2h(v.x) | ((uint)f2h(v.y) << 16);
        p.y = (uint)f2h(v.z) | ((uint)f2h(v.w) << 16);
        int slot = q4 >> 1;
        *reinterpret_cast<uint2*>(&sB[row * 128 + ((slot ^ (row & 7)) << 3) + (q4 & 1) * 4]) = p;
    }
    __syncthreads();

    f32x4 acc[2][8];
#pragma unroll
    for (int rf = 0; rf < 2; ++rf)
#pragma unroll
        for (int cf = 0; cf < 8; ++cf) acc[rf][cf] = (f32x4){0.f, 0.f, 0.f, 0.f};

    half8 aF[2][4];
#pragma unroll
    for (int rf = 0; rf < 2; ++rf) {
        int row = w * 32 + rf * 16 + lr;
#pragma unroll
        for (int kc = 0; kc < 4; ++kc) {
            int slot = kc * 4 + lk;
            aF[rf][kc] = *reinterpret_cast<const half8*>(&sA[row * 128 + ((slot ^ (row & 7)) << 3)]);
        }
    }
#pragma unroll
    for (int cf = 0; cf < 8; ++cf) {
        int col = cf * 16 + lr;
#pragma unroll
        for (int kc = 0; kc < 4; ++kc) {
            int slot = kc * 4 + lk;
            half8 bF = *reinterpret_cast<const half8*>(&sB[col * 128 + ((slot ^ (col & 7)) << 3)]);
            acc[0][cf] = __builtin_amdgcn_mfma_f32_16x16x32_f16(aF[0][kc], bF, acc[0][cf], 0, 0, 0);
            acc[1][cf] = __builtin_amdgcn_mfma_f32_16x16x32_f16(aF[1][kc], bF, acc[1][cf], 0, 0, 0);
        }
    }
    __syncthreads();

    ushort* sOut = sA;
#pragma unroll
    for (int rf = 0; rf < 2; ++rf)
#pragma unroll
        for (int cf = 0; cf < 8; ++cf)
#pragma unroll
            for (int reg = 0; reg < 4; ++reg) {
                int row = w * 32 + rf * 16 + lk * 4 + reg;
                int col = cf * 16 + lr;
                sOut[row * 128 + col] = f2h(acc[rf][cf][reg]);
            }
    __syncthreads();
#pragma unroll
    for (int i = 0; i < 8; ++i) {
        int fid = i * 256 + t;
        int row = fid >> 4, q = fid & 15;
        int gr = row0 + row;
        if (gr < M)
            reinterpret_cast<uint4*>(Out)[(size_t)gr * 16 + q] =
                *reinterpret_cast<const uint4*>(&sOut[row * 128 + q * 8]);
    }
}

// ---------------- Fused SpMM1 + MLP2: P = tanh(SpMM(A,XW1)) @ W2^T ----------------
// Round-11 version verbatim (measured 70.7us): 16 rows/block, 4 waves x 4 rows,
// register accumulation, staged sW2, one barrier before MFMA.

__global__ __launch_bounds__(256) void spmm1_fused_kernel(const int2* __restrict__ ep,
                                                          const int* __restrict__ row_ptr,
                                                          const int* __restrict__ row_len,
                                                          const uint* __restrict__ T,
                                                          const uint* __restrict__ W2h,
                                                          uint* __restrict__ Ph, int M) {
    __shared__ __align__(16) ushort sH[16 * 128];   // 4 KB, slot^(row&7) swizzled
    __shared__ __align__(16) ushort sW2[64 * 128];  // 16 KB, swizzled
    __shared__ __align__(16) ushort sP[16 * 64];    // 2 KB, row-major

    const int t = threadIdx.x;
    const int l = t & 63;
    const int w = t >> 6;
    const int lr = l & 15;
    const int lk = l >> 4;
    const int row0 = blockIdx.x * 16;

    // stage W2 (swizzled)
#pragma unroll
    for (int i = 0; i < 4; ++i) {
        int fid = i * 256 + t;
        int row = fid >> 4, slot = fid & 15;
        uint4 v = reinterpret_cast<const uint4*>(W2h)[row * 16 + slot];
        *reinterpret_cast<uint4*>(&sW2[row * 128 + ((slot ^ (row & 7)) << 3)]) = v;
    }

    // gather phase: wave w handles local rows w*4 .. w*4+3 (register accumulation)
    uint* sHu = reinterpret_cast<uint*>(sH);
#pragma unroll
    for (int rr = 0; rr < 4; ++rr) {
        const int lrow = w * 4 + rr;
        const int r = row0 + lrow;
        float a0x = 0.f, a0y = 0.f, a1x = 0.f, a1y = 0.f;
        if (r < M) {
            int beg = row_ptr[r];
            int end = beg + row_len[r];
            for (int e = beg; e < end; e += 8) {
                int2 cv[8];
                uint xu[8];
#pragma unroll
                for (int i = 0; i < 8; ++i) cv[i] = ep[e + i];
#pragma unroll
                for (int i = 0; i < 8; ++i) xu[i] = T[(size_t)(cv[i].x & 0x1FFFF) * 64 + l];
#pragma unroll
                for (int i = 0; i < 8; ++i) {
                    float v = __int_as_float(cv[i].y);
                    __half2 h2 = *reinterpret_cast<__half2*>(&xu[i]);
                    float2 f = __half22float2(h2);
                    if (i & 1) { a1x += v * f.x; a1y += v * f.y; }
                    else       { a0x += v * f.x; a0y += v * f.y; }
                }
            }
        }
        // lane l holds dims 2l, 2l+1 of H row lrow -> slot l>>2, uint pos l&3
        uint hv = (uint)f2h(tanhf(a0x + a1x)) | ((uint)f2h(tanhf(a0y + a1y)) << 16);
        int slot = l >> 2;
        sHu[lrow * 64 + ((slot ^ (lrow & 7)) << 2) + (l & 3)] = hv;
    }
    __syncthreads();

    // MFMA phase: wave w -> P[0:16, w*16..+15]
    f32x4 acc = (f32x4){0.f, 0.f, 0.f, 0.f};
    const int col = w * 16 + lr;
#pragma unroll
    for (int kc = 0; kc < 4; ++kc) {
        int slot = kc * 4 + lk;
        half8 aF = *reinterpret_cast<const half8*>(&sH[lr * 128 + ((slot ^ (lr & 7)) << 3)]);
        half8 bF = *reinterpret_cast<const half8*>(&sW2[col * 128 + ((slot ^ (col & 7)) << 3)]);
        acc = __builtin_amdgcn_mfma_f32_16x16x32_f16(aF, bF, acc, 0, 0, 0);
    }
    // C layout: col = l&15, row = (l>>4)*4 + reg
#pragma unroll
    for (int reg = 0; reg < 4; ++reg)
        sP[(lk * 4 + reg) * 64 + col] = f2h(acc[reg]);
    __syncthreads();

    // coalesced copy-out: 16 rows x 8 uint4
    if (t < 128) {
        const int row = t >> 3, q = t & 7;
        const int gr = row0 + row;
        if (gr < M)
            reinterpret_cast<uint4*>(Ph)[(size_t)gr * 8 + q] =
                *reinterpret_cast<const uint4*>(&sP[row * 64 + q * 8]);
    }
}

// ---------------- SpMM 64-dim f16 gather + tanh -> f32 out (tail-free) ----------------

__global__ __launch_bounds__(256) void spmm2_kernel(const int2* __restrict__ ep,
                                                    const int* __restrict__ row_ptr,
                                                    const int* __restrict__ row_len,
                                                    const ushort* __restrict__ Ph,
                                                    float* __restrict__ out) {
    int wave = threadIdx.x >> 6;
    int lane = threadIdx.x & 63;
    int r = blockIdx.x * 4 + wave;
    if (r >= N_NODES) return;
    int beg = row_ptr[r];
    int end = beg + row_len[r];
    float acc0 = 0.f, acc1 = 0.f;
    for (int e = beg; e < end; e += 8) {
        int2 cv[8];
        ushort xu[8];
#pragma unroll
        for (int i = 0; i < 8; ++i) cv[i] = ep[e + i];
#pragma unroll
        for (int i = 0; i < 8; ++i) xu[i] = Ph[(size_t)(cv[i].x & 0x1FFFF) * 64 + lane];
#pragma unroll
        for (int i = 0; i < 8; ++i) {
            float v = __int_as_float(cv[i].y);
            __half h = *reinterpret_cast<__half*>(&xu[i]);
            float x = __half2float(h);
            if (i & 1) acc1 += v * x;
            else       acc0 += v * x;
        }
    }
    out[(size_t)r * DIM_OUT + lane] = tanhf(acc0 + acc1);
}

// ---------------- launch ----------------

extern "C" void kernel_launch(void* const* d_in, const int* in_sizes, int n_in,
                              void* d_out, int out_size, void* d_ws, size_t ws_size,
                              hipStream_t stream) {
    const float* X = (const float*)d_in[0];
    const float* W1 = (const float*)d_in[1];
    const float* W2 = (const float*)d_in[2];
    const float* evals = (const float*)d_in[3];
    const int* erow = (const int*)d_in[4];
    const int* ecol = (const int*)d_in[5];
    float* out = (float*)d_out;

    const int N = N_NODES;
    const int E = N_EDGES;

    char* ws = (char*)d_ws;
    size_t off = 0;
    auto alloc = [&](size_t bytes) {
        size_t o = off;
        off = (off + bytes + 255) & ~(size_t)255;
        return o;
    };
    size_t o_counts = alloc((size_t)NB * NCHUNK * 4);
    size_t o_offnb = alloc((size_t)NB * NCHUNK * 4);
    size_t o_tot = alloc((size_t)NB * 4);
    size_t o_bbase = alloc((size_t)(NB + 1) * 4);
    size_t o_rowptr = alloc((size_t)N * 4);
    size_t o_rowlen = alloc((size_t)N * 4);
    size_t o_ep = alloc((size_t)NB * EPCAP * 8);  // 19.2MB padded CSR
    size_t o_key = alloc((size_t)E * 4);
    size_t o_val = alloc((size_t)E * 4);
    size_t o_xw1 = alloc((size_t)N * 64 * 4);  // XW1h [N,128] f16
    size_t o_ph = alloc((size_t)N * 32 * 4);   // Ph   [N,64]  f16
    size_t o_w2h = alloc((size_t)64 * 64 * 4);
    (void)ws_size;

    int* counts = (int*)(ws + o_counts);
    int* offnb = (int*)(ws + o_offnb);
    int* tot = (int*)(ws + o_tot);
    int* bbase = (int*)(ws + o_bbase);
    int* row_ptr = (int*)(ws + o_rowptr);
    int* row_len = (int*)(ws + o_rowlen);
    int2* ep = (int2*)(ws + o_ep);
    uint* keyOut = (uint*)(ws + o_key);
    float* valOut = (float*)(ws + o_val);
    uint* XW1h = (uint*)(ws + o_xw1);
    uint* Ph = (uint*)(ws + o_ph);
    uint* W2h = (uint*)(ws + o_w2h);

    const int gemm_grid = (N + 127) / 128;  // 782
    const int spmm2_grid = (N + 3) / 4;     // 25000
    const int fused_grid = N / 16;          // 6250 (exact)

    // XW1 = f16(X @ W1^T)  [W1 converted inline during staging]
    mfma_gemm128_kernel<<<gemm_grid, 256, 0, stream>>>(X, W1, XW1h, N);

    // CSR build (deterministic counting sort; rows padded to multiples of 8).
    // chunk_hist also produces W2h (block 0).
    chunk_hist_kernel<<<NCHUNK, 256, 0, stream>>>(erow, counts, W2, W2h, E);
    bucket_scan_kernel<<<NB, 512, 0, stream>>>(counts, offnb, tot);
    base_scan_kernel<<<1, 512, 0, stream>>>(tot, bbase);
    coarse_scatter_kernel<<<NCHUNK, 512, 0, stream>>>(erow, ecol, evals, offnb, bbase,
                                                      keyOut, valOut, E);
    fine_sort_kernel<<<NB, 256, 0, stream>>>(keyOut, valOut, bbase, row_ptr, row_len, ep);

    // P = tanh(SpMM(A, XW1)) @ W2^T   [fused, round-11 structure]
    spmm1_fused_kernel<<<fused_grid, 256, 0, stream>>>(ep, row_ptr, row_len, XW1h, W2h, Ph, N);
    // out = tanh(SpMM(A, P))
    spmm2_kernel<<<spmm2_grid, 256, 0, stream>>>(ep, row_ptr, row_len, (const ushort*)Ph, out);
}